// Round 4
// baseline (995.398 us; speedup 1.0000x reference)
//
#include <hip/hip_runtime.h>
#include <cstddef>

#define NN 100000
#define NE 1600000
#define BSH 8                      // bucket shift: 256 nodes/bucket
#define NB  ((NN + 255) >> BSH)    // 391 buckets
#define BIN_DEPTH 16
#define SORT_DEPTH 5120            // mean bucket 4096 edges, +16 sigma
#define BINA_BLOCKS 128

typedef unsigned int uint;
typedef unsigned short ushort;
typedef short bf16x8 __attribute__((ext_vector_type(8)));
typedef float f32x16 __attribute__((ext_vector_type(16)));

__device__ inline uint bf16_rne(float f) {   // fp32 -> bf16 bits (round-nearest-even)
  uint u = __float_as_uint(f);
  u += 0x7fffu + ((u >> 16) & 1u);
  return u >> 16;
}

// ---------------- degree count + bucket histogram (fused) ----------------
__global__ void __launch_bounds__(256) k_count(const int* __restrict__ dst,
                                               uint* __restrict__ cnt,
                                               uint* __restrict__ gbcnt) {
  __shared__ uint lb[NB];
  int t = threadIdx.x;
  for (int j = t; j < NB; j += 256) lb[j] = 0;
  __syncthreads();
  int base = blockIdx.x * 4096;
  #pragma unroll 4
  for (int r = 0; r < 16; ++r) {
    int i = base + r * 256 + t;
    if (i < NE) {
      int d = dst[i];
      atomicAdd(&cnt[d], 1u);
      atomicAdd(&lb[d >> BSH], 1u);
    }
  }
  __syncthreads();
  for (int j = t; j < NB; j += 256) if (lb[j]) atomicAdd(&gbcnt[j], lb[j]);
}

__global__ void __launch_bounds__(256) k_dis(const uint* __restrict__ cnt,
                                             float* __restrict__ dis, int N) {
  int i = blockIdx.x * 256 + threadIdx.x;
  if (i < N) dis[i] = rsqrtf((float)cnt[i] + 1.0f);
}

// ---------------- bucket-base exclusive scan (391 values, one block) ----------------
__global__ void __launch_bounds__(512) k_bscan(const uint* __restrict__ gbcnt,
                                               int* __restrict__ bbase,
                                               int* __restrict__ gcur,
                                               int* __restrict__ row_ptr) {
  __shared__ uint s[512];
  int t = threadIdx.x;
  uint v = (t < NB) ? gbcnt[t] : 0u;
  s[t] = v;
  __syncthreads();
  for (int off = 1; off < 512; off <<= 1) {
    uint add = (t >= off) ? s[t - off] : 0u;
    __syncthreads();
    s[t] += add;
    __syncthreads();
  }
  if (t < NB) { int e = (int)(s[t] - v); bbase[t] = e; gcur[t] = e; }
  if (t == 0) { bbase[NB] = NE; row_ptr[NN] = NE; }
}

// ---------------- pass A: LDS-binned partition by bucket (full-line flushes) ----------------
__global__ void __launch_bounds__(256) k_binA(const int* __restrict__ src,
                                              const int* __restrict__ dst,
                                              int* __restrict__ gcur,
                                              int2* __restrict__ ebuf) {
  __shared__ int2 bins[NB][BIN_DEPTH];   // ~50 KB
  __shared__ uint bcnt[NB];
  int t = threadIdx.x, lane = t & 63, wv = t >> 6;
  for (int j = t; j < NB; j += 256) bcnt[j] = 0;
  const int per = (NE + BINA_BLOCKS - 1) / BINA_BLOCKS;   // 12500 (even)
  int e0 = blockIdx.x * per;
  int e1 = min(NE, e0 + per);
  const int2* src2 = reinterpret_cast<const int2*>(src);
  const int2* dst2 = reinterpret_cast<const int2*>(dst);
  __syncthreads();
  for (int rbase = e0; rbase < e1; rbase += 512) {
    int i = rbase + t * 2;
    if (i < e1) {                      // e1 even -> pair never splits
      int2 sp = src2[i >> 1];
      int2 dp = dst2[i >> 1];
      #pragma unroll
      for (int j = 0; j < 2; ++j) {
        int s = j ? sp.y : sp.x;
        int d = j ? dp.y : dp.x;
        int b = d >> BSH;
        uint slot = atomicAdd(&bcnt[b], 1u);
        if (slot < BIN_DEPTH) bins[b][slot] = make_int2(s, d);
        else { int pos = atomicAdd(&gcur[b], 1); ebuf[pos] = make_int2(s, d); }
      }
    }
    __syncthreads();
    // flush multiples of 8 entries (64 B lines), keep remainder
    for (int b = wv; b < NB; b += 4) {
      uint cb = bcnt[b]; if (cb > BIN_DEPTH) cb = BIN_DEPTH;
      uint nf = cb & ~7u;
      if (nf) {
        int base;
        if (lane == 0) base = atomicAdd(&gcur[b], (int)nf);
        base = __shfl(base, 0, 64);
        if (lane < (int)nf) ebuf[base + lane] = bins[b][lane];
        uint rem = cb - nf;
        int2 tmp;
        if (lane < (int)rem) tmp = bins[b][nf + lane];   // src idx >= 8 > dst idx <= 6: no overlap
        if (lane < (int)rem) bins[b][lane] = tmp;
        if (lane == 0) bcnt[b] = rem;
      } else if (lane == 0) {
        bcnt[b] = cb;   // clamp any spill-inflated count
      }
    }
    __syncthreads();
  }
  // final drain
  for (int b = wv; b < NB; b += 4) {
    uint cb = bcnt[b]; if (cb > BIN_DEPTH) cb = BIN_DEPTH;
    if (cb) {
      int base;
      if (lane == 0) base = atomicAdd(&gcur[b], (int)cb);
      base = __shfl(base, 0, 64);
      if (lane < (int)cb) ebuf[base + lane] = bins[b][lane];
    }
  }
}

// ---------------- pass B: per-bucket LDS counting sort -> final CSR + row_ptr ----------------
__global__ void __launch_bounds__(256) k_sortB(const int2* __restrict__ ebuf,
                                               const int* __restrict__ bbase,
                                               const float* __restrict__ dis,
                                               int* __restrict__ row_ptr,
                                               int2* __restrict__ edges) {
  __shared__ int2 sbuf[SORT_DEPTH];      // 40 KB
  __shared__ uint lcnt[256], lcur[256], s[256];
  __shared__ float disl[256];
  int b = blockIdx.x, t = threadIdx.x;
  int node0 = b << BSH;
  int ebeg = bbase[b], eend = bbase[b + 1];
  lcnt[t] = 0;
  int gnode = node0 + t;
  disl[t] = (gnode < NN) ? dis[gnode] : 0.f;
  __syncthreads();
  for (int i = ebeg + t; i < eend; i += 256)
    atomicAdd(&lcnt[ebuf[i].y & 255], 1u);
  __syncthreads();
  uint v = lcnt[t]; s[t] = v;
  __syncthreads();
  for (int off = 1; off < 256; off <<= 1) {
    uint add = (t >= off) ? s[t - off] : 0u;
    __syncthreads();
    s[t] += add;
    __syncthreads();
  }
  uint excl = s[t] - v;
  lcur[t] = excl;
  if (gnode < NN) row_ptr[gnode] = ebeg + (int)excl;
  __syncthreads();
  for (int i = ebeg + t; i < eend; i += 256) {
    int2 e = ebuf[i];
    int li = e.y & 255;
    uint pos = atomicAdd(&lcur[li], 1u);
    int2 rec = make_int2(e.x, __float_as_int(dis[e.x] * disl[li]));
    if (pos < SORT_DEPTH) sbuf[pos] = rec;
    else edges[ebeg + pos] = rec;        // overflow fallback: exact slot, rare
  }
  __syncthreads();
  int cntE = eend - ebeg;
  for (int j = t; j < cntE; j += 256)
    edges[ebeg + j] = sbuf[j];
}

// ---------------- MFMA bf16 GEMM: Hb[M][FOUT](bf16) = X[M][128] @ W[128][FOUT] ----------------
// M-tile 64, 4 waves; wave w: row-half (w&1), col-group (w>>1). 32x32x16 MFMA.
template <int FOUT>
__global__ void __launch_bounds__(256) k_gemm(const float* __restrict__ X,
                                              const float* __restrict__ W,
                                              ushort* __restrict__ Hb, int M) {
  constexpr int NCT = FOUT / 32;          // col-tiles: 4 (F=128) or 2
  constexpr int TPW = NCT / 2;            // tiles per wave: 2 or 1
  __shared__ alignas(16) ushort Af[2 * 8 * 64 * 8];      // 16 KB
  __shared__ alignas(16) ushort Wf[NCT * 8 * 64 * 8];    // 32 or 16 KB
  int t = threadIdx.x, lane = t & 63, wv = t >> 6;
  int m0 = blockIdx.x * 64;

  // stage A (fragment order): thread t -> row t>>2, k-groups (t&3)+4i
  {
    int m = t >> 2;
    int gm = m0 + m;
    int rb = m >> 5, ml = m & 31;
    #pragma unroll
    for (int i = 0; i < 4; ++i) {
      int g = (t & 3) + i * 4;            // g = k>>3 in 0..15
      float4 va = make_float4(0.f, 0.f, 0.f, 0.f), vb = va;
      if (gm < M) {
        va = *reinterpret_cast<const float4*>(X + (size_t)gm * 128 + g * 8);
        vb = *reinterpret_cast<const float4*>(X + (size_t)gm * 128 + g * 8 + 4);
      }
      uint4 p;
      p.x = bf16_rne(va.x) | (bf16_rne(va.y) << 16);
      p.y = bf16_rne(va.z) | (bf16_rne(va.w) << 16);
      p.z = bf16_rne(vb.x) | (bf16_rne(vb.y) << 16);
      p.w = bf16_rne(vb.z) | (bf16_rne(vb.w) << 16);
      int kc = g >> 1, khi = g & 1;
      int ln = khi * 32 + ml;
      *reinterpret_cast<uint4*>(&Af[(((rb * 8 + kc) * 64) + ln) * 8]) = p;
    }
  }
  // stage W (fragment order, transposed scatter)
  {
    constexpr int ITERS = 128 * FOUT / 4 / 256;
    #pragma unroll
    for (int it = 0; it < ITERS; ++it) {
      int lin = it * 256 + t;
      int k = lin / (FOUT / 4);
      int n = (lin % (FOUT / 4)) * 4;
      float4 vw = *reinterpret_cast<const float4*>(W + (size_t)k * FOUT + n);
      int kc = k >> 4, khi = (k >> 3) & 1, j = k & 7;
      float arr[4] = {vw.x, vw.y, vw.z, vw.w};
      #pragma unroll
      for (int e = 0; e < 4; ++e) {
        int nn = n + e;
        int c = nn >> 5;
        int ln = khi * 32 + (nn & 31);
        Wf[(((c * 8 + kc) * 64) + ln) * 8 + j] = (ushort)bf16_rne(arr[e]);
      }
    }
  }
  __syncthreads();

  f32x16 acc[TPW];
  #pragma unroll
  for (int tp = 0; tp < TPW; ++tp)
    #pragma unroll
    for (int r = 0; r < 16; ++r) acc[tp][r] = 0.f;

  int rb = wv & 1, cg = wv >> 1;
  #pragma unroll
  for (int kc = 0; kc < 8; ++kc) {
    bf16x8 a = *reinterpret_cast<bf16x8*>(&Af[((rb * 8 + kc) * 64 + lane) * 8]);
    #pragma unroll
    for (int tp = 0; tp < TPW; ++tp) {
      int c = cg * TPW + tp;
      bf16x8 bb = *reinterpret_cast<bf16x8*>(&Wf[((c * 8 + kc) * 64 + lane) * 8]);
      acc[tp] = __builtin_amdgcn_mfma_f32_32x32x16_bf16(a, bb, acc[tp], 0, 0, 0);
    }
  }

  // epilogue: C/D layout col=lane&31, row=(reg&3)+8*(reg>>2)+4*(lane>>5)
  #pragma unroll
  for (int tp = 0; tp < TPW; ++tp) {
    int col = (cg * TPW + tp) * 32 + (lane & 31);
    #pragma unroll
    for (int reg = 0; reg < 16; ++reg) {
      int row = m0 + rb * 32 + 4 * (lane >> 5) + (reg & 3) + 8 * (reg >> 2);
      if (row < M) Hb[(size_t)row * FOUT + col] = (ushort)bf16_rne(acc[tp][reg]);
    }
  }
}

// ---------------- aggregate: bf16 gather (neighbors + self), fp32 accum ----------------
template <int F, bool RELU, bool LSM>
__global__ void __launch_bounds__(256) k_agg(const uint* __restrict__ hb,
                                             const int* __restrict__ row_ptr,
                                             const int2* __restrict__ edges,
                                             const float* __restrict__ dis,
                                             const float* __restrict__ bias,
                                             float* __restrict__ out, int N) {
  int n = blockIdx.x * 4 + (threadIdx.x >> 6);
  int lane = threadIdx.x & 63;
  if (n >= N) return;
  int beg = row_ptr[n], end = row_ptr[n + 1];

  if (F == 128) {
    float2 acc = make_float2(0.f, 0.f);
    int p = beg;
    for (; p + 8 <= end; p += 8) {
      int2 e[8];
      #pragma unroll
      for (int j = 0; j < 8; ++j) e[j] = edges[p + j];
      uint v[8];
      #pragma unroll
      for (int j = 0; j < 8; ++j) v[j] = hb[(size_t)e[j].x * 64 + lane];
      #pragma unroll
      for (int j = 0; j < 8; ++j) {
        float c = __int_as_float(e[j].y);
        acc.x = fmaf(__uint_as_float(v[j] << 16), c, acc.x);
        acc.y = fmaf(__uint_as_float(v[j] & 0xffff0000u), c, acc.y);
      }
    }
    if (p + 4 <= end) {
      int2 e[4];
      #pragma unroll
      for (int j = 0; j < 4; ++j) e[j] = edges[p + j];
      uint v[4];
      #pragma unroll
      for (int j = 0; j < 4; ++j) v[j] = hb[(size_t)e[j].x * 64 + lane];
      #pragma unroll
      for (int j = 0; j < 4; ++j) {
        float c = __int_as_float(e[j].y);
        acc.x = fmaf(__uint_as_float(v[j] << 16), c, acc.x);
        acc.y = fmaf(__uint_as_float(v[j] & 0xffff0000u), c, acc.y);
      }
      p += 4;
    }
    for (; p < end; ++p) {
      int2 e = edges[p];
      float c = __int_as_float(e.y);
      uint v = hb[(size_t)e.x * 64 + lane];
      acc.x = fmaf(__uint_as_float(v << 16), c, acc.x);
      acc.y = fmaf(__uint_as_float(v & 0xffff0000u), c, acc.y);
    }
    float dn = dis[n];
    float sc = dn * dn;
    uint hv = hb[(size_t)n * 64 + lane];
    float2 b = reinterpret_cast<const float2*>(bias)[lane];
    acc.x = fmaf(sc, __uint_as_float(hv << 16), acc.x) + b.x;
    acc.y = fmaf(sc, __uint_as_float(hv & 0xffff0000u), acc.y) + b.y;
    if (RELU) { acc.x = fmaxf(acc.x, 0.f); acc.y = fmaxf(acc.y, 0.f); }
    reinterpret_cast<float2*>(out)[(size_t)n * 64 + lane] = acc;
  } else {
    const ushort* __restrict__ hbs = reinterpret_cast<const ushort*>(hb);
    float acc = 0.f;
    int p = beg;
    for (; p + 8 <= end; p += 8) {
      int2 e[8];
      #pragma unroll
      for (int j = 0; j < 8; ++j) e[j] = edges[p + j];
      ushort v[8];
      #pragma unroll
      for (int j = 0; j < 8; ++j) v[j] = hbs[(size_t)e[j].x * 64 + lane];
      #pragma unroll
      for (int j = 0; j < 8; ++j)
        acc = fmaf(__uint_as_float((uint)v[j] << 16), __int_as_float(e[j].y), acc);
    }
    for (; p < end; ++p) {
      int2 e = edges[p];
      ushort v = hbs[(size_t)e.x * 64 + lane];
      acc = fmaf(__uint_as_float((uint)v << 16), __int_as_float(e.y), acc);
    }
    float dn = dis[n];
    ushort hv = hbs[(size_t)n * 64 + lane];
    acc = fmaf(dn * dn, __uint_as_float((uint)hv << 16), acc) + bias[lane];
    if (RELU) acc = fmaxf(acc, 0.f);
    if (LSM) {
      float m = acc;
      #pragma unroll
      for (int d = 32; d; d >>= 1) m = fmaxf(m, __shfl_xor(m, d, 64));
      float e = expf(acc - m);
      #pragma unroll
      for (int d = 32; d; d >>= 1) e += __shfl_xor(e, d, 64);
      acc = acc - m - logf(e);
    }
    out[(size_t)n * 64 + lane] = acc;
  }
}

extern "C" void kernel_launch(void* const* d_in, const int* in_sizes, int n_in,
                              void* d_out, int out_size, void* d_ws, size_t ws_size,
                              hipStream_t stream) {
  const float* x  = (const float*)d_in[0];
  const int*   ei = (const int*)d_in[1];
  const float* W0 = (const float*)d_in[2];
  const float* b0 = (const float*)d_in[3];
  const float* W1 = (const float*)d_in[4];
  const float* b1 = (const float*)d_in[5];
  const float* W2 = (const float*)d_in[6];
  const float* b2 = (const float*)d_in[7];
  float* out = (float*)d_out;

  const int N = NN, E = NE;
  const int* src = ei;
  const int* dst = ei + E;

  char* ws = (char*)d_ws;
  size_t off = 0;
  auto alloc = [&](size_t bytes) -> void* {
    off = (off + 255) & ~(size_t)255;
    void* p = ws + off;
    off += bytes;
    return p;
  };
  uint*  cnt     = (uint*)alloc((size_t)(N + NB) * 4);  // cnt[N] + gbcnt[NB] adjacent
  uint*  gbcnt   = cnt + N;
  float* dis     = (float*)alloc((size_t)N * 4);
  int*   bbase   = (int*)alloc((size_t)(NB + 1) * 4);
  int*   gcur    = (int*)alloc((size_t)NB * 4);
  int*   row_ptr = (int*)alloc((size_t)(N + 1) * 4);
  int2*  ebuf    = (int2*)alloc((size_t)E * 8);
  int2*  edges   = (int2*)alloc((size_t)E * 8);
  ushort* bufAb  = (ushort*)alloc((size_t)N * 128 * 2);  // bf16 GEMM out
  float*  bufB   = (float*)alloc((size_t)N * 128 * 4);   // agg out / next gemm in

  // ---- CSR build ----
  hipMemsetAsync(cnt, 0, (size_t)(N + NB) * 4, stream);
  k_count<<<(E + 4095) / 4096, 256, 0, stream>>>(dst, cnt, gbcnt);
  k_dis<<<(N + 255) / 256, 256, 0, stream>>>(cnt, dis, N);
  k_bscan<<<1, 512, 0, stream>>>(gbcnt, bbase, gcur, row_ptr);
  k_binA<<<BINA_BLOCKS, 256, 0, stream>>>(src, dst, gcur, ebuf);
  k_sortB<<<NB, 256, 0, stream>>>(ebuf, bbase, dis, row_ptr, edges);

  const int gemm_grid = (N + 63) / 64;   // 1563
  const int node_grid = (N + 3) / 4;     // 25000

  // ---- layer 0 ----
  k_gemm<128><<<gemm_grid, 256, 0, stream>>>(x, W0, bufAb, N);
  k_agg<128, true, false><<<node_grid, 256, 0, stream>>>((const uint*)bufAb, row_ptr, edges, dis, b0, bufB, N);
  // ---- layer 1 ----
  k_gemm<128><<<gemm_grid, 256, 0, stream>>>(bufB, W1, bufAb, N);
  k_agg<128, true, false><<<node_grid, 256, 0, stream>>>((const uint*)bufAb, row_ptr, edges, dis, b1, bufB, N);
  // ---- layer 2 (fused log_softmax epilogue) ----
  k_gemm<64><<<gemm_grid, 256, 0, stream>>>(bufB, W2, bufAb, N);
  k_agg<64, false, true><<<node_grid, 256, 0, stream>>>((const uint*)bufAb, row_ptr, edges, dis, b2, out, N);
}

// Round 5
// 550.796 us; speedup vs baseline: 1.8072x; 1.8072x over previous
//
#include <hip/hip_runtime.h>
#include <cstddef>

#define NN 100000
#define NE 1600000

typedef unsigned int uint;
typedef unsigned short ushort;
typedef short bf16x8 __attribute__((ext_vector_type(8)));
typedef float f32x16 __attribute__((ext_vector_type(16)));

__device__ inline uint bf16_rne(float f) {   // fp32 -> bf16 bits (round-nearest-even)
  uint u = __float_as_uint(f);
  u += 0x7fffu + ((u >> 16) & 1u);
  return u >> 16;
}

// ---------------- degree count ----------------
__global__ void __launch_bounds__(256) k_count(const int* __restrict__ dst,
                                               uint* __restrict__ cnt, int E) {
  int i = blockIdx.x * 256 + threadIdx.x;
  if (i < E) atomicAdd(&cnt[dst[i]], 1u);
}

__global__ void __launch_bounds__(256) k_dis(const uint* __restrict__ cnt,
                                             float* __restrict__ dis, int N) {
  int i = blockIdx.x * 256 + threadIdx.x;
  if (i < N) dis[i] = rsqrtf((float)cnt[i] + 1.0f);
}

// ---------------- 3-pass scan ----------------
__global__ void __launch_bounds__(1024) k_scan1(const uint* __restrict__ cnt,
                                                uint* __restrict__ bsum, int N) {
  __shared__ uint ws[16];
  int tid = threadIdx.x;
  int i = blockIdx.x * 1024 + tid;
  uint v = (i < N) ? cnt[i] : 0u;
  #pragma unroll
  for (int d = 32; d; d >>= 1) v += __shfl_xor(v, d, 64);
  if ((tid & 63) == 0) ws[tid >> 6] = v;
  __syncthreads();
  if (tid == 0) {
    uint s = 0;
    #pragma unroll
    for (int j = 0; j < 16; ++j) s += ws[j];
    bsum[blockIdx.x] = s;
  }
}

__global__ void __launch_bounds__(128) k_scan2(const uint* __restrict__ bsum,
                                               uint* __restrict__ boff, int nb,
                                               int* __restrict__ row_ptr, int N, int E) {
  __shared__ uint w0tot;
  int tid = threadIdx.x, lane = tid & 63, wv = tid >> 6;
  uint v = (tid < nb) ? bsum[tid] : 0u;
  uint x = v;
  #pragma unroll
  for (int d = 1; d < 64; d <<= 1) {
    uint y = __shfl_up(x, (uint)d, 64);
    if (lane >= d) x += y;
  }
  if (wv == 0 && lane == 63) w0tot = x;
  __syncthreads();
  uint excl = (x - v) + (wv ? w0tot : 0u);
  if (tid < nb) boff[tid] = excl;
  if (tid == 0) row_ptr[N] = E;
}

__global__ void __launch_bounds__(1024) k_scan3(const uint* __restrict__ cnt,
                                                const uint* __restrict__ boff,
                                                int* __restrict__ row_ptr,
                                                int* __restrict__ cursor, int N) {
  __shared__ uint ws[16];
  __shared__ uint wexcl[16];
  int tid = threadIdx.x, lane = tid & 63, wv = tid >> 6;
  int i = blockIdx.x * 1024 + tid;
  uint v = (i < N) ? cnt[i] : 0u;
  uint x = v;
  #pragma unroll
  for (int d = 1; d < 64; d <<= 1) {
    uint y = __shfl_up(x, (uint)d, 64);
    if (lane >= d) x += y;
  }
  if (lane == 63) ws[wv] = x;
  __syncthreads();
  if (tid == 0) {
    uint run = 0;
    #pragma unroll
    for (int j = 0; j < 16; ++j) { uint t = ws[j]; wexcl[j] = run; run += t; }
  }
  __syncthreads();
  uint excl = boff[blockIdx.x] + wexcl[wv] + (x - v);
  if (i < N) { row_ptr[i] = (int)excl; cursor[i] = (int)excl; }
}

// ---------------- scatter edges into CSR order, packed (src, coef) ----------------
__global__ void __launch_bounds__(256) k_scatter(const int* __restrict__ src,
                                                 const int* __restrict__ dst,
                                                 const float* __restrict__ dis,
                                                 int* __restrict__ cursor,
                                                 int2* __restrict__ edges, int E) {
  int i = blockIdx.x * 256 + threadIdx.x;
  if (i < E) {
    int s = src[i], d = dst[i];
    int pos = atomicAdd(&cursor[d], 1);
    edges[pos] = make_int2(s, __float_as_int(dis[s] * dis[d]));
  }
}

// ---------------- MFMA bf16 GEMM: Hb[M][FOUT](bf16) = X[M][128] @ W[128][FOUT] ----------------
// M-tile 64, 4 waves; wave w: row-half (w&1), col-group (w>>1). 32x32x16 MFMA.
template <int FOUT>
__global__ void __launch_bounds__(256) k_gemm(const float* __restrict__ X,
                                              const float* __restrict__ W,
                                              ushort* __restrict__ Hb, int M) {
  constexpr int NCT = FOUT / 32;          // col-tiles: 4 (F=128) or 2
  constexpr int TPW = NCT / 2;            // tiles per wave: 2 or 1
  __shared__ alignas(16) ushort Af[2 * 8 * 64 * 8];      // 16 KB
  __shared__ alignas(16) ushort Wf[NCT * 8 * 64 * 8];    // 32 or 16 KB
  int t = threadIdx.x, lane = t & 63, wv = t >> 6;
  int m0 = blockIdx.x * 64;

  // stage A (fragment order): thread t -> row t>>2, k-groups (t&3)+4i
  {
    int m = t >> 2;
    int gm = m0 + m;
    int rb = m >> 5, ml = m & 31;
    #pragma unroll
    for (int i = 0; i < 4; ++i) {
      int g = (t & 3) + i * 4;            // g = k>>3 in 0..15
      float4 va = make_float4(0.f, 0.f, 0.f, 0.f), vb = va;
      if (gm < M) {
        va = *reinterpret_cast<const float4*>(X + (size_t)gm * 128 + g * 8);
        vb = *reinterpret_cast<const float4*>(X + (size_t)gm * 128 + g * 8 + 4);
      }
      uint4 p;
      p.x = bf16_rne(va.x) | (bf16_rne(va.y) << 16);
      p.y = bf16_rne(va.z) | (bf16_rne(va.w) << 16);
      p.z = bf16_rne(vb.x) | (bf16_rne(vb.y) << 16);
      p.w = bf16_rne(vb.z) | (bf16_rne(vb.w) << 16);
      int kc = g >> 1, khi = g & 1;
      int ln = khi * 32 + ml;
      *reinterpret_cast<uint4*>(&Af[(((rb * 8 + kc) * 64) + ln) * 8]) = p;
    }
  }
  // stage W (fragment order, transposed scatter)
  {
    constexpr int ITERS = 128 * FOUT / 4 / 256;
    #pragma unroll
    for (int it = 0; it < ITERS; ++it) {
      int lin = it * 256 + t;
      int k = lin / (FOUT / 4);
      int n = (lin % (FOUT / 4)) * 4;
      float4 vw = *reinterpret_cast<const float4*>(W + (size_t)k * FOUT + n);
      int kc = k >> 4, khi = (k >> 3) & 1, j = k & 7;
      float arr[4] = {vw.x, vw.y, vw.z, vw.w};
      #pragma unroll
      for (int e = 0; e < 4; ++e) {
        int nn = n + e;
        int c = nn >> 5;
        int ln = khi * 32 + (nn & 31);
        Wf[(((c * 8 + kc) * 64) + ln) * 8 + j] = (ushort)bf16_rne(arr[e]);
      }
    }
  }
  __syncthreads();

  f32x16 acc[TPW];
  #pragma unroll
  for (int tp = 0; tp < TPW; ++tp)
    #pragma unroll
    for (int r = 0; r < 16; ++r) acc[tp][r] = 0.f;

  int rb = wv & 1, cg = wv >> 1;
  #pragma unroll
  for (int kc = 0; kc < 8; ++kc) {
    bf16x8 a = *reinterpret_cast<bf16x8*>(&Af[((rb * 8 + kc) * 64 + lane) * 8]);
    #pragma unroll
    for (int tp = 0; tp < TPW; ++tp) {
      int c = cg * TPW + tp;
      bf16x8 bb = *reinterpret_cast<bf16x8*>(&Wf[((c * 8 + kc) * 64 + lane) * 8]);
      acc[tp] = __builtin_amdgcn_mfma_f32_32x32x16_bf16(a, bb, acc[tp], 0, 0, 0);
    }
  }

  // epilogue: C/D layout col=lane&31, row=(reg&3)+8*(reg>>2)+4*(lane>>5)
  #pragma unroll
  for (int tp = 0; tp < TPW; ++tp) {
    int col = (cg * TPW + tp) * 32 + (lane & 31);
    #pragma unroll
    for (int reg = 0; reg < 16; ++reg) {
      int row = m0 + rb * 32 + 4 * (lane >> 5) + (reg & 3) + 8 * (reg >> 2);
      if (row < M) Hb[(size_t)row * FOUT + col] = (ushort)bf16_rne(acc[tp][reg]);
    }
  }
}

// ---------------- aggregate: bf16 gather (neighbors + self), fp32 accum ----------------
template <int F, bool RELU, bool LSM>
__global__ void __launch_bounds__(256) k_agg(const uint* __restrict__ hb,
                                             const int* __restrict__ row_ptr,
                                             const int2* __restrict__ edges,
                                             const float* __restrict__ dis,
                                             const float* __restrict__ bias,
                                             float* __restrict__ out, int N) {
  int n = blockIdx.x * 4 + (threadIdx.x >> 6);
  int lane = threadIdx.x & 63;
  if (n >= N) return;
  int beg = row_ptr[n], end = row_ptr[n + 1];

  if (F == 128) {
    float2 acc = make_float2(0.f, 0.f);
    int p = beg;
    for (; p + 8 <= end; p += 8) {
      int2 e[8];
      #pragma unroll
      for (int j = 0; j < 8; ++j) e[j] = edges[p + j];
      uint v[8];
      #pragma unroll
      for (int j = 0; j < 8; ++j) v[j] = hb[(size_t)e[j].x * 64 + lane];
      #pragma unroll
      for (int j = 0; j < 8; ++j) {
        float c = __int_as_float(e[j].y);
        acc.x = fmaf(__uint_as_float(v[j] << 16), c, acc.x);
        acc.y = fmaf(__uint_as_float(v[j] & 0xffff0000u), c, acc.y);
      }
    }
    if (p + 4 <= end) {
      int2 e[4];
      #pragma unroll
      for (int j = 0; j < 4; ++j) e[j] = edges[p + j];
      uint v[4];
      #pragma unroll
      for (int j = 0; j < 4; ++j) v[j] = hb[(size_t)e[j].x * 64 + lane];
      #pragma unroll
      for (int j = 0; j < 4; ++j) {
        float c = __int_as_float(e[j].y);
        acc.x = fmaf(__uint_as_float(v[j] << 16), c, acc.x);
        acc.y = fmaf(__uint_as_float(v[j] & 0xffff0000u), c, acc.y);
      }
      p += 4;
    }
    for (; p < end; ++p) {
      int2 e = edges[p];
      float c = __int_as_float(e.y);
      uint v = hb[(size_t)e.x * 64 + lane];
      acc.x = fmaf(__uint_as_float(v << 16), c, acc.x);
      acc.y = fmaf(__uint_as_float(v & 0xffff0000u), c, acc.y);
    }
    float dn = dis[n];
    float sc = dn * dn;
    uint hv = hb[(size_t)n * 64 + lane];
    float2 b = reinterpret_cast<const float2*>(bias)[lane];
    acc.x = fmaf(sc, __uint_as_float(hv << 16), acc.x) + b.x;
    acc.y = fmaf(sc, __uint_as_float(hv & 0xffff0000u), acc.y) + b.y;
    if (RELU) { acc.x = fmaxf(acc.x, 0.f); acc.y = fmaxf(acc.y, 0.f); }
    reinterpret_cast<float2*>(out)[(size_t)n * 64 + lane] = acc;
  } else {
    const ushort* __restrict__ hbs = reinterpret_cast<const ushort*>(hb);
    float acc = 0.f;
    int p = beg;
    for (; p + 8 <= end; p += 8) {
      int2 e[8];
      #pragma unroll
      for (int j = 0; j < 8; ++j) e[j] = edges[p + j];
      ushort v[8];
      #pragma unroll
      for (int j = 0; j < 8; ++j) v[j] = hbs[(size_t)e[j].x * 64 + lane];
      #pragma unroll
      for (int j = 0; j < 8; ++j)
        acc = fmaf(__uint_as_float((uint)v[j] << 16), __int_as_float(e[j].y), acc);
    }
    for (; p < end; ++p) {
      int2 e = edges[p];
      ushort v = hbs[(size_t)e.x * 64 + lane];
      acc = fmaf(__uint_as_float((uint)v << 16), __int_as_float(e.y), acc);
    }
    float dn = dis[n];
    ushort hv = hbs[(size_t)n * 64 + lane];
    acc = fmaf(dn * dn, __uint_as_float((uint)hv << 16), acc) + bias[lane];
    if (RELU) acc = fmaxf(acc, 0.f);
    if (LSM) {
      float m = acc;
      #pragma unroll
      for (int d = 32; d; d >>= 1) m = fmaxf(m, __shfl_xor(m, d, 64));
      float e = expf(acc - m);
      #pragma unroll
      for (int d = 32; d; d >>= 1) e += __shfl_xor(e, d, 64);
      acc = acc - m - logf(e);
    }
    out[(size_t)n * 64 + lane] = acc;
  }
}

extern "C" void kernel_launch(void* const* d_in, const int* in_sizes, int n_in,
                              void* d_out, int out_size, void* d_ws, size_t ws_size,
                              hipStream_t stream) {
  const float* x  = (const float*)d_in[0];
  const int*   ei = (const int*)d_in[1];
  const float* W0 = (const float*)d_in[2];
  const float* b0 = (const float*)d_in[3];
  const float* W1 = (const float*)d_in[4];
  const float* b1 = (const float*)d_in[5];
  const float* W2 = (const float*)d_in[6];
  const float* b2 = (const float*)d_in[7];
  float* out = (float*)d_out;

  const int N = NN, E = NE;
  const int* src = ei;
  const int* dst = ei + E;

  char* ws = (char*)d_ws;
  size_t off = 0;
  auto alloc = [&](size_t bytes) -> void* {
    off = (off + 255) & ~(size_t)255;
    void* p = ws + off;
    off += bytes;
    return p;
  };
  uint*   cnt     = (uint*)alloc((size_t)N * 4);
  float*  dis     = (float*)alloc((size_t)N * 4);
  int*    row_ptr = (int*)alloc((size_t)(N + 1) * 4);
  int*    cursor  = (int*)alloc((size_t)N * 4);
  int2*   edges   = (int2*)alloc((size_t)E * 8);
  uint*   bsum    = (uint*)alloc(128 * 4);
  uint*   boff    = (uint*)alloc(128 * 4);
  ushort* bufAb   = (ushort*)alloc((size_t)N * 128 * 2);  // bf16 GEMM out
  float*  bufB    = (float*)alloc((size_t)N * 128 * 4);   // agg out / next gemm in

  const int nb = (N + 1023) / 1024;  // 98

  // ---- CSR build ----
  hipMemsetAsync(cnt, 0, (size_t)N * 4, stream);
  k_count<<<(E + 255) / 256, 256, 0, stream>>>(dst, cnt, E);
  k_dis<<<(N + 255) / 256, 256, 0, stream>>>(cnt, dis, N);
  k_scan1<<<nb, 1024, 0, stream>>>(cnt, bsum, N);
  k_scan2<<<1, 128, 0, stream>>>(bsum, boff, nb, row_ptr, N, E);
  k_scan3<<<nb, 1024, 0, stream>>>(cnt, boff, row_ptr, cursor, N);
  k_scatter<<<(E + 255) / 256, 256, 0, stream>>>(src, dst, dis, cursor, edges, E);

  const int gemm_grid = (N + 63) / 64;   // 1563
  const int node_grid = (N + 3) / 4;     // 25000

  // ---- layer 0 ----
  k_gemm<128><<<gemm_grid, 256, 0, stream>>>(x, W0, bufAb, N);
  k_agg<128, true, false><<<node_grid, 256, 0, stream>>>((const uint*)bufAb, row_ptr, edges, dis, b0, bufB, N);
  // ---- layer 1 ----
  k_gemm<128><<<gemm_grid, 256, 0, stream>>>(bufB, W1, bufAb, N);
  k_agg<128, true, false><<<node_grid, 256, 0, stream>>>((const uint*)bufAb, row_ptr, edges, dis, b1, bufB, N);
  // ---- layer 2 (fused log_softmax epilogue) ----
  k_gemm<64><<<gemm_grid, 256, 0, stream>>>(bufB, W2, bufAb, N);
  k_agg<64, false, true><<<node_grid, 256, 0, stream>>>((const uint*)bufAb, row_ptr, edges, dis, b2, out, N);
}